// Round 4
// baseline (144.817 us; speedup 1.0000x reference)
//
#include <hip/hip_runtime.h>

namespace {
constexpr int BLOCK = 256;
constexpr int GRID = 1024;     // 4 blocks/CU persistent; 4 sweeps over 1M quads
constexpr int PSTRIDE = 1024;  // partial column stride == max grid
constexpr float WPF = 4.0f;
constexpr float LN2 = 0.69314718055994531f;
constexpr float LOG2E = 1.44269504088896340f;
// part layout (ws, [14][PSTRIDE] floats, column-major per stat):
// j0=S13 (sum (y4-yt), t<4, log2)  j1..4=li_c  j5=liN  j6..9=cnt_c  j10..13=nsel_c
// R6: no per-block __threadfence finalize (per-XCD L2 writeback storm).
// R9: sched_barrier(0) after load issue or the compiler sinks loads to save VGPRs.
// R10: one-shot kernels can't pipeline — persistent grid + iterations.
// R11: dispatch/atomic overhead ~0.7 us. R12: coalescing neutral (pattern
// exonerated). R13: 24 waves/CU neutral-negative (occupancy exonerated).
// R14 theory: WRITE_SIZE is a TCC counter (L2->fabric), so the 2x320MB poison
// fills leave the 256MB L3 full of DIRTY poison. main's 96MB cold reads then
// evict dirty victims -> ~96MB of HBM writeback rides along with the 96MB
// read = 2x traffic = the observed 34us/2.9TB/s. Fix: nt (non-temporal,
// no-allocate) loads -> no L3 allocation -> no poison writeback during main.
}

typedef float f4 __attribute__((ext_vector_type(4)));
typedef int i4 __attribute__((ext_vector_type(4)));

struct Quad { f4 v0, v1, v2, v3, v4; i4 tt; };

__device__ __forceinline__ float wave_reduce(float v) {
#pragma unroll
    for (int o = 32; o > 0; o >>= 1) v += __shfl_down(v, o, 64);
    return v;
}

__global__ __launch_bounds__(BLOCK) void mpu_main(const float* __restrict__ x,
                                                  const int* __restrict__ t,
                                                  float* __restrict__ part, int N) {
    __shared__ float red[BLOCK / 64][16];

    float S13 = 0.f, li0 = 0.f, li1 = 0.f, li2 = 0.f, li3 = 0.f, liN = 0.f;
    int c0 = 0, c1 = 0, c2 = 0, c3 = 0, n0 = 0, n1 = 0, n2 = 0, n3 = 0;

    // log2-domain; no max-subtraction (|x|<~6.5 for N(0,1): exp2-safe).
    auto process = [&](float x0, float x1, float x2, float x3, float x4, int tc) {
        const float y0 = x0 * LOG2E, y1 = x1 * LOG2E, y2 = x2 * LOG2E,
                    y3 = x3 * LOG2E, y4 = x4 * LOG2E;
        const float f0 = __builtin_amdgcn_exp2f(y0);
        const float f1 = __builtin_amdgcn_exp2f(y1);
        const float f2 = __builtin_amdgcn_exp2f(y2);
        const float f3 = __builtin_amdgcn_exp2f(y3);
        const float f4_ = __builtin_amdgcn_exp2f(y4);
        const float s = ((f0 + f1) + (f2 + f3)) + f4_;   // sum e^{x_i}
        const float L2 = __builtin_amdgcn_logf(s);       // log2(sum)
        const float thr = L2 - 1.0f;
        // "all p<=0.5" is ymax <= log2(s)-1 with unnormalized s (R5 bug).
        const float ymax = fmaxf(fmaxf(fmaxf(y0, y1), fmaxf(y2, y3)), y4);
        const float yt = (tc == 0) ? y0 : (tc == 1) ? y1 : (tc == 2) ? y2
                       : (tc == 3) ? y3 : y4;
        const float nltY = L2 - yt;                      // -log2(p_t)
        const float nlnY = L2 - y4;                      // -log2(p_neg)
        const bool sel = (yt > thr);                     // p_t > 0.5
        const bool alle = (ymax <= thr);                 // all p <= 0.5
        const bool tpos = (tc < 4);
        S13 += tpos ? (y4 - yt) : 0.f;                   // risk1-risk3 collapse
        const float cv = sel ? nlnY * __builtin_amdgcn_exp2f(nltY) : 0.f;
        li0 += (tc == 0) ? cv : 0.f;
        li1 += (tc == 1) ? cv : 0.f;
        li2 += (tc == 2) ? cv : 0.f;
        li3 += (tc == 3) ? cv : 0.f;
        liN += (tc == 4 && alle) ? nlnY : 0.f;

        const unsigned long long b0 = __ballot(tc == 0);
        const unsigned long long b1 = __ballot(tc == 1);
        const unsigned long long b2 = __ballot(tc == 2);
        const unsigned long long b3 = __ballot(tc == 3);
        const unsigned long long bs = __ballot(sel);
        c0 += (int)__popcll(b0);
        c1 += (int)__popcll(b1);
        c2 += (int)__popcll(b2);
        c3 += (int)__popcll(b3);
        n0 += (int)__popcll(bs & b0);
        n1 += (int)__popcll(bs & b1);
        n2 += (int)__popcll(bs & b2);
        n3 += (int)__popcll(bs & b3);
    };

    auto load_quad = [&](int g, Quad& q) {
        // nt: non-temporal (no-allocate/evict-first). Keeps main's read misses
        // from allocating L3 lines and evicting the fills' dirty poison (R14).
        const f4* xv = reinterpret_cast<const f4*>(x) + (size_t)g * 5;
        q.v0 = __builtin_nontemporal_load(xv + 0);
        q.v1 = __builtin_nontemporal_load(xv + 1);
        q.v2 = __builtin_nontemporal_load(xv + 2);
        q.v3 = __builtin_nontemporal_load(xv + 3);
        q.v4 = __builtin_nontemporal_load(xv + 4);
        q.tt = __builtin_nontemporal_load(reinterpret_cast<const i4*>(t) + g);
    };

    auto process4 = [&](const Quad& q) {
        process(q.v0.x, q.v0.y, q.v0.z, q.v0.w, q.v1.x, q.tt.x);
        process(q.v1.y, q.v1.z, q.v1.w, q.v2.x, q.v2.y, q.tt.y);
        process(q.v2.z, q.v2.w, q.v3.x, q.v3.y, q.v3.z, q.tt.z);
        process(q.v3.w, q.v4.x, q.v4.y, q.v4.z, q.v4.w, q.tt.w);
    };

    const int pid = blockIdx.x * BLOCK + threadIdx.x;
    const int S = gridDim.x * BLOCK;
    const int nQuad = N >> 2;
    const int niter = (nQuad + S - 1) / S;               // uniform across threads

    Quad A, B;
    if (pid < nQuad) load_quad(pid, A);
    for (int it = 0; it < niter; it += 2) {
        const int g1 = pid + (it + 1) * S;
        if (g1 < nQuad) load_quad(g1, B);                // prefetch next
        __builtin_amdgcn_sched_barrier(0);               // pin loads above compute
        const int gA = pid + it * S;
        if (gA < nQuad) process4(A);
        const int g2 = pid + (it + 2) * S;
        if (g2 < nQuad) load_quad(g2, A);                // prefetch next-next
        __builtin_amdgcn_sched_barrier(0);
        if (g1 < nQuad) process4(B);
    }

    // tail rows (N % 4): single lane; ballots correct under 1-lane exec
    if (blockIdx.x == 0 && threadIdx.x == 0) {
        for (int k = (N >> 2) << 2; k < N; ++k)
            process(x[k * 5 + 0], x[k * 5 + 1], x[k * 5 + 2], x[k * 5 + 3],
                    x[k * 5 + 4], t[k]);
    }

    const int wv = threadIdx.x >> 6, ln = threadIdx.x & 63;
    float fr[6] = {S13, li0, li1, li2, li3, liN};
#pragma unroll
    for (int j = 0; j < 6; ++j) {
        const float v = wave_reduce(fr[j]);
        if (ln == 0) red[wv][j] = v;
    }
    if (ln == 0) {   // counts are wave-uniform after ballot/popc
        red[wv][6] = (float)c0;   red[wv][7] = (float)c1;
        red[wv][8] = (float)c2;   red[wv][9] = (float)c3;
        red[wv][10] = (float)n0;  red[wv][11] = (float)n1;
        red[wv][12] = (float)n2;  red[wv][13] = (float)n3;
    }
    __syncthreads();
    if (threadIdx.x < 14) {
        const float v = red[0][threadIdx.x] + red[1][threadIdx.x] +
                        red[2][threadIdx.x] + red[3][threadIdx.x];
        // plain store to distinct slot; stream-order kernel boundary is the
        // cross-XCD fence (producer->consumer). No atomics, no pre-zeroing.
        part[threadIdx.x * PSTRIDE + blockIdx.x] = v;
    }
}

__global__ __launch_bounds__(896) void mpu_final(const float* __restrict__ part,
                                                 float* __restrict__ out,
                                                 int nb, int N) {
    // 14 waves: wave w sums partial column w (contiguous, coalesced).
    __shared__ float red[16];
    const int w = threadIdx.x >> 6, ln = threadIdx.x & 63;
    float s = 0.f;
    for (int b = ln; b < nb; b += 64) s += part[w * PSTRIDE + b];
    s = wave_reduce(s);
    if (ln == 0) red[w] = s;
    __syncthreads();
    if (threadIdx.x == 0) {
        const float invN = 1.0f / (float)N;
        // S13 accumulated (y4-yt) = LOG2E*(x4-xt) -> multiply by LN2.
        const float risk13 = LN2 * red[0] * invN;
        float risk2 = 0.0f;
#pragma unroll
        for (int c = 0; c < 4; ++c)
            risk2 += (red[6 + c] * invN) *
                     (LN2 * red[1 + c] / fmaxf(red[10 + c], 1.0f));
        const float c4 = (float)N - (red[6] + red[7] + red[8] + red[9]);
        const float risk4 = LN2 * red[5] / fmaxf(c4, 1.0f);
        float pos = WPF * (risk13 + risk2);
        if (pos < 0.0f) pos = 0.0f;
        out[0] = pos + risk4;
    }
}

extern "C" void kernel_launch(void* const* d_in, const int* in_sizes, int n_in,
                              void* d_out, int out_size, void* d_ws, size_t ws_size,
                              hipStream_t stream) {
    const float* x = (const float*)d_in[0];
    const int* t = (const int*)d_in[1];
    float* out = (float*)d_out;
    float* part = (float*)d_ws;
    const int N = in_sizes[1];

    const int nQuad = N >> 2;
    int grid = (nQuad + BLOCK - 1) / BLOCK;
    if (grid > GRID) grid = GRID;
    if (grid < 1) grid = 1;
    mpu_main<<<grid, BLOCK, 0, stream>>>(x, t, part, N);
    mpu_final<<<1, 896, 0, stream>>>(part, out, grid, N);
}

// Round 5
// 132.153 us; speedup vs baseline: 1.0958x; 1.0958x over previous
//
#include <hip/hip_runtime.h>

namespace {
constexpr int BLOCK = 256;
constexpr int GRID = 1024;     // 4 blocks/CU persistent; 4 sweeps over 1M quads
constexpr int PSTRIDE = 1024;  // partial column stride == max grid
constexpr float WPF = 4.0f;
constexpr float LN2 = 0.69314718055994531f;
constexpr float LOG2E = 1.44269504088896340f;
// part layout (ws, [14][PSTRIDE] floats, column-major per stat):
// j0=S13 (sum (y4-yt), t<4, log2)  j1..4=li_c  j5=liN  j6..9=cnt_c  j10..13=nsel_c
// R6: no per-block __threadfence finalize. R9: sched_barrier(0) after load
// issue. R10: persistent grid. R11: dispatch overhead ~0.7us. R12: coalescing
// neutral. R13: occupancy neutral. R14: nt on the 80B-stride pattern was
// CONFOUNDED (-5x line reuse) -> +10us; theory not tested.
// R15: clean probe. R12's LDS-staged loads touch each 128B line EXACTLY once
// (contiguous 4KB chunks/instruction), so nt can't lose reuse. If the fills'
// dirty poison in L3 is what doubles main's HBM traffic (alloc->dirty-victim
// writeback), nt-no-allocate removes it: main ~34 -> ~18us. If neutral, ~2.9
// TB/s is the intrinsic read ceiling here -> roofline.
}

typedef float f4 __attribute__((ext_vector_type(4)));
typedef int i4 __attribute__((ext_vector_type(4)));

__device__ __forceinline__ float wave_reduce(float v) {
#pragma unroll
    for (int o = 32; o > 0; o >>= 1) v += __shfl_down(v, o, 64);
    return v;
}

__global__ __launch_bounds__(BLOCK) void mpu_main(const float* __restrict__ x,
                                                  const int* __restrict__ t,
                                                  float* __restrict__ part, int N) {
    __shared__ f4 tile[BLOCK * 5];          // 20 KB: 256 quads (1024 rows) of x
    __shared__ float red[BLOCK / 64][16];

    float S13 = 0.f, li0 = 0.f, li1 = 0.f, li2 = 0.f, li3 = 0.f, liN = 0.f;
    int c0 = 0, c1 = 0, c2 = 0, c3 = 0, n0 = 0, n1 = 0, n2 = 0, n3 = 0;

    // log2-domain; no max-subtraction (|x|<~6.5 for N(0,1): exp2-safe).
    auto process = [&](float x0, float x1, float x2, float x3, float x4, int tc) {
        const float y0 = x0 * LOG2E, y1 = x1 * LOG2E, y2 = x2 * LOG2E,
                    y3 = x3 * LOG2E, y4 = x4 * LOG2E;
        const float f0 = __builtin_amdgcn_exp2f(y0);
        const float f1 = __builtin_amdgcn_exp2f(y1);
        const float f2 = __builtin_amdgcn_exp2f(y2);
        const float f3 = __builtin_amdgcn_exp2f(y3);
        const float f4_ = __builtin_amdgcn_exp2f(y4);
        const float s = ((f0 + f1) + (f2 + f3)) + f4_;   // sum e^{x_i}
        const float L2 = __builtin_amdgcn_logf(s);       // log2(sum)
        const float thr = L2 - 1.0f;
        // "all p<=0.5" is ymax <= log2(s)-1 with unnormalized s (R5 bug).
        const float ymax = fmaxf(fmaxf(fmaxf(y0, y1), fmaxf(y2, y3)), y4);
        const float yt = (tc == 0) ? y0 : (tc == 1) ? y1 : (tc == 2) ? y2
                       : (tc == 3) ? y3 : y4;
        const float nltY = L2 - yt;                      // -log2(p_t)
        const float nlnY = L2 - y4;                      // -log2(p_neg)
        const bool sel = (yt > thr);                     // p_t > 0.5
        const bool alle = (ymax <= thr);                 // all p <= 0.5
        const bool tpos = (tc < 4);
        S13 += tpos ? (y4 - yt) : 0.f;                   // risk1-risk3 collapse
        const float cv = sel ? nlnY * __builtin_amdgcn_exp2f(nltY) : 0.f;
        li0 += (tc == 0) ? cv : 0.f;
        li1 += (tc == 1) ? cv : 0.f;
        li2 += (tc == 2) ? cv : 0.f;
        li3 += (tc == 3) ? cv : 0.f;
        liN += (tc == 4 && alle) ? nlnY : 0.f;

        const unsigned long long b0 = __ballot(tc == 0);
        const unsigned long long b1 = __ballot(tc == 1);
        const unsigned long long b2 = __ballot(tc == 2);
        const unsigned long long b3 = __ballot(tc == 3);
        const unsigned long long bs = __ballot(sel);
        c0 += (int)__popcll(b0);
        c1 += (int)__popcll(b1);
        c2 += (int)__popcll(b2);
        c3 += (int)__popcll(b3);
        n0 += (int)__popcll(bs & b0);
        n1 += (int)__popcll(bs & b1);
        n2 += (int)__popcll(bs & b2);
        n3 += (int)__popcll(bs & b3);
    };

    const int tid = threadIdx.x;
    const int S = gridDim.x * BLOCK;
    const int nQuad = N >> 2;
    const int nF4 = nQuad * 5;               // float4 count of x (quad region)
    const int niter = (nQuad + S - 1) / S;   // uniform across threads
    const f4* __restrict__ xv4 = reinterpret_cast<const f4*>(x);
    const i4* __restrict__ tv4 = reinterpret_cast<const i4*>(t);

    // Next-tile staging registers (reg prefetch; written to LDS at loop top).
    f4 R0, R1, R2, R3, R4;
    i4 Rt;
    auto issue = [&](int it) {
        const int tstart = blockIdx.x * BLOCK + it * S;  // tile's first quad
        const int fb = tstart * 5 + tid;                 // coalesced: lane stride 16B
        // nt loads: each 128B line is read exactly once in this pattern, so
        // no reuse to lose; no L3 allocation -> no dirty-poison victim
        // writebacks (R15 probe).
        if (fb < nF4)        R0 = __builtin_nontemporal_load(xv4 + fb);
        if (fb + 256 < nF4)  R1 = __builtin_nontemporal_load(xv4 + fb + 256);
        if (fb + 512 < nF4)  R2 = __builtin_nontemporal_load(xv4 + fb + 512);
        if (fb + 768 < nF4)  R3 = __builtin_nontemporal_load(xv4 + fb + 768);
        if (fb + 1024 < nF4) R4 = __builtin_nontemporal_load(xv4 + fb + 1024);
        if (tstart + tid < nQuad) Rt = __builtin_nontemporal_load(tv4 + tstart + tid);
    };

    issue(0);
    for (int it = 0; it < niter; ++it) {
        __syncthreads();                     // prev tile reads done; LDS writable
        // write staged regs -> LDS (LDS idx m holds float4 tstart*5+m)
        tile[tid] = R0;
        tile[tid + 256] = R1;
        tile[tid + 512] = R2;
        tile[tid + 768] = R3;
        tile[tid + 1024] = R4;
        const i4 myT = Rt;                   // capture before reissue clobbers Rt
        const int tstart = blockIdx.x * BLOCK + it * S;
        const bool valid = (tstart + tid) < nQuad;
        if (it + 1 < niter) issue(it + 1);   // prefetch next tile into regs
        __builtin_amdgcn_sched_barrier(0);   // pin loads above compute (R9)
        __syncthreads();                     // tile visible to all waves
        if (valid) {
            // own quad: bytes tid*80.. — lanes 0..7 cover all 32 banks: conflict-free
            const f4 v0 = tile[tid * 5 + 0];
            const f4 v1 = tile[tid * 5 + 1];
            const f4 v2 = tile[tid * 5 + 2];
            const f4 v3 = tile[tid * 5 + 3];
            const f4 v4 = tile[tid * 5 + 4];
            process(v0.x, v0.y, v0.z, v0.w, v1.x, myT.x);
            process(v1.y, v1.z, v1.w, v2.x, v2.y, myT.y);
            process(v2.z, v2.w, v3.x, v3.y, v3.z, myT.z);
            process(v3.w, v4.x, v4.y, v4.z, v4.w, myT.w);
        }
    }

    // tail rows (N % 4): single lane; ballots correct under 1-lane exec
    if (blockIdx.x == 0 && threadIdx.x == 0) {
        for (int k = (N >> 2) << 2; k < N; ++k)
            process(x[k * 5 + 0], x[k * 5 + 1], x[k * 5 + 2], x[k * 5 + 3],
                    x[k * 5 + 4], t[k]);
    }

    const int wv = threadIdx.x >> 6, ln = threadIdx.x & 63;
    float fr[6] = {S13, li0, li1, li2, li3, liN};
#pragma unroll
    for (int j = 0; j < 6; ++j) {
        const float v = wave_reduce(fr[j]);
        if (ln == 0) red[wv][j] = v;
    }
    if (ln == 0) {   // counts are wave-uniform after ballot/popc
        red[wv][6] = (float)c0;   red[wv][7] = (float)c1;
        red[wv][8] = (float)c2;   red[wv][9] = (float)c3;
        red[wv][10] = (float)n0;  red[wv][11] = (float)n1;
        red[wv][12] = (float)n2;  red[wv][13] = (float)n3;
    }
    __syncthreads();
    if (threadIdx.x < 14) {
        const float v = red[0][threadIdx.x] + red[1][threadIdx.x] +
                        red[2][threadIdx.x] + red[3][threadIdx.x];
        // plain store to distinct slot; stream-order kernel boundary is the
        // cross-XCD fence (producer->consumer). No atomics, no pre-zeroing.
        part[threadIdx.x * PSTRIDE + blockIdx.x] = v;
    }
}

__global__ __launch_bounds__(896) void mpu_final(const float* __restrict__ part,
                                                 float* __restrict__ out,
                                                 int nb, int N) {
    // 14 waves: wave w sums partial column w (contiguous, coalesced).
    __shared__ float red[16];
    const int w = threadIdx.x >> 6, ln = threadIdx.x & 63;
    float s = 0.f;
    for (int b = ln; b < nb; b += 64) s += part[w * PSTRIDE + b];
    s = wave_reduce(s);
    if (ln == 0) red[w] = s;
    __syncthreads();
    if (threadIdx.x == 0) {
        const float invN = 1.0f / (float)N;
        // S13 accumulated (y4-yt) = LOG2E*(x4-xt) -> multiply by LN2.
        const float risk13 = LN2 * red[0] * invN;
        float risk2 = 0.0f;
#pragma unroll
        for (int c = 0; c < 4; ++c)
            risk2 += (red[6 + c] * invN) *
                     (LN2 * red[1 + c] / fmaxf(red[10 + c], 1.0f));
        const float c4 = (float)N - (red[6] + red[7] + red[8] + red[9]);
        const float risk4 = LN2 * red[5] / fmaxf(c4, 1.0f);
        float pos = WPF * (risk13 + risk2);
        if (pos < 0.0f) pos = 0.0f;
        out[0] = pos + risk4;
    }
}

extern "C" void kernel_launch(void* const* d_in, const int* in_sizes, int n_in,
                              void* d_out, int out_size, void* d_ws, size_t ws_size,
                              hipStream_t stream) {
    const float* x = (const float*)d_in[0];
    const int* t = (const int*)d_in[1];
    float* out = (float*)d_out;
    float* part = (float*)d_ws;
    const int N = in_sizes[1];

    const int nQuad = N >> 2;
    int grid = (nQuad + BLOCK - 1) / BLOCK;
    if (grid > GRID) grid = GRID;
    if (grid < 1) grid = 1;
    mpu_main<<<grid, BLOCK, 0, stream>>>(x, t, part, N);
    mpu_final<<<1, 896, 0, stream>>>(part, out, grid, N);
}